// Round 10
// baseline (284.592 us; speedup 1.0000x reference)
//
#include <hip/hip_runtime.h>
#include <hip/hip_bf16.h>

// Problem constants (B=1)
#define T_ 8
#define H_ 64
#define W_ 64
#define C_ 64
#define HW_ (H_ * W_)          // 4096
#define THW_ (T_ * H_ * W_)    // 32768
#define KTAPS 27
#define KDIM (C_ * KTAPS)      // 1728
#define NOFF 54
#define CHS 70                 // padded LDS channel stride (bf16): 35 dwords, gcd(35,32)=1

typedef __bf16 bf16x8 __attribute__((ext_vector_type(8)));
typedef float floatx4 __attribute__((ext_vector_type(4)));

// ---------------------------------------------------------------------------
// prep: swizzle weights into MFMA B-fragment order so kernel B-loads are
// wave-uniform-base + lane*16B (fully coalesced).
//  ws[tap*4096 + g16*1024 + s*512 + lane*8 + j]
//    = W[co = g16*16 + (lane&15)][cin = s*32 + (lane>>4)*8 + j][tap]
// ---------------------------------------------------------------------------
__global__ void prep_kernel(const float* __restrict__ w1, const float* __restrict__ woff,
                            const float* __restrict__ wd, const float* __restrict__ wr,
                            __hip_bfloat16* __restrict__ w1s, __hip_bfloat16* __restrict__ woffs,
                            __hip_bfloat16* __restrict__ wds, __hip_bfloat16* __restrict__ wrs) {
    int i = blockIdx.x * 256 + threadIdx.x;
    if (i < C_ * KDIM) {
        int j = i & 7, lane = (i >> 3) & 63, s = (i >> 9) & 1, g16 = (i >> 10) & 3, tap = i >> 12;
        int co = g16 * 16 + (lane & 15);
        int cin = s * 32 + (lane >> 4) * 8 + j;
        int src = (co * C_ + cin) * KTAPS + tap;
        w1s[i] = __float2bfloat16(w1[src]);
        woffs[i] = (co < NOFF) ? __float2bfloat16(woff[src]) : __float2bfloat16(0.f);
        wds[i] = __float2bfloat16(wd[src]);
    }
    if (i < C_ * C_) {
        int j = i & 7, lane = (i >> 3) & 63, s = (i >> 9) & 1, g16 = i >> 10;
        int co = g16 * 16 + (lane & 15);
        int cin = s * 32 + (lane >> 4) * 8 + j;
        wrs[i] = __float2bfloat16(wr[co * C_ + cin]);
    }
}

// ---------------------------------------------------------------------------
// x (64,T,H,W) fp32 cf -> xcl (T,H,W,64) bf16 cl, via LDS 64x64 transpose tile
// ---------------------------------------------------------------------------
__global__ __launch_bounds__(256) void to_cl_kernel(const float* __restrict__ x,
                                                    __hip_bfloat16* __restrict__ xcl) {
    __shared__ float tile[64][65];
    const int pos0 = blockIdx.x * 64;
    const int tid = threadIdx.x;
    for (int i = tid; i < 4096; i += 256) {
        int ch = i >> 6, p = i & 63;
        tile[ch][p] = x[ch * THW_ + pos0 + p];
    }
    __syncthreads();
    for (int i = tid; i < 4096; i += 256) {
        int p = i >> 6, ch = i & 63;
        xcl[(pos0 + p) * C_ + ch] = __float2bfloat16(tile[ch][p]);
    }
}

// ---------------------------------------------------------------------------
// MFMA implicit-GEMM 3x3x3 conv, pad=1. UNCHANGED from passing R9.
// ---------------------------------------------------------------------------
template <bool CONV1>
__global__ __launch_bounds__(256) void conv_mfma_kernel(
    const __hip_bfloat16* __restrict__ in_cl,
    const __hip_bfloat16* __restrict__ wTs,   // swizzled (27*4096)
    const float* __restrict__ bias,
    __hip_bfloat16* __restrict__ out_cl_b16,  // CONV1: (T,H,W,64)
    float* __restrict__ out_cf,               // !CONV1: (NCO,T,H,W)
    int nco) {
    __shared__ float smem[2380];              // 2 x (34*70) bf16 = 9520B; reused ts[32][68]
    __hip_bfloat16* Ab = (__hip_bfloat16*)smem;

    const int tid = threadIdx.x;
    const int wv = tid >> 6;
    const int lane = tid & 63;
    const int l15 = lane & 15;
    const int quad = lane >> 4;
    const int wh = blockIdx.x & 1;
    const int h = (blockIdx.x >> 1) & 63;
    const int t = blockIdx.x >> 7;
    const int w0 = wh * 32;
    const int n = wv * 16 + l15;
    const int slot = tid >> 2;                // staging slot 0..33 (threads 0..135)
    const int c16 = tid & 3;
    const bool stager = tid < 136;

    floatx4 acc[2];
#pragma unroll
    for (int m = 0; m < 2; ++m) acc[m] = (floatx4){0.f, 0.f, 0.f, 0.f};

    const int ktlo = (t == 0) ? 1 : 0;
    const int kthi = (t == T_ - 1) ? 2 : 3;
    const int nr = (kthi - ktlo) * 3;         // 6 or 9 rows

    bf16x8 ra = {}, rb = {};
    auto load_row = [&](int r, bf16x8& a, bf16x8& b) {
        a = (bf16x8){};
        b = (bf16x8){};
        if (!stager) return;
        const int kt = ktlo + r / 3, kh = r % 3;
        const int h_in = h - 1 + kh;
        const int t_in = t - 1 + kt;
        const int w_in = w0 - 1 + slot;
        if ((unsigned)h_in < H_ && (unsigned)w_in < W_) {
            const __hip_bfloat16* p = in_cl + ((t_in * HW_ + h_in * W_) + w_in) * C_ + c16 * 16;
            a = *(const bf16x8*)(p);
            b = *(const bf16x8*)(p + 8);
        }
    };

    bf16x8 cb[6], nb[6];
    const __hip_bfloat16* wbase = wTs + wv * 1024 + lane * 8;
    auto loadB = [&](int r, bf16x8* B) {
        const int kt = ktlo + r / 3, kh = r % 3;
        const int tapb = kt * 9 + kh * 3;
#pragma unroll
        for (int kw = 0; kw < 3; ++kw) {
            const __hip_bfloat16* p = wbase + (tapb + kw) * 4096;
            B[kw * 2] = *(const bf16x8*)(p);
            B[kw * 2 + 1] = *(const bf16x8*)(p + 512);
        }
    };

    // prologue: stage row 0, prefetch row 1 (A) and rows 0,1 (B)
    load_row(0, ra, rb);
    loadB(0, cb);
    if (stager) {
        *(bf16x8*)&Ab[slot * CHS + c16 * 16] = ra;
        *(bf16x8*)&Ab[slot * CHS + c16 * 16 + 8] = rb;
    }
    load_row(1, ra, rb);
    loadB(1, nb);
    __syncthreads();

    for (int r = 0; r < nr; ++r) {
        __hip_bfloat16* buf = Ab + (r & 1) * 34 * CHS;
        if (r + 1 < nr) {                      // stage next row into other buffer
            __hip_bfloat16* bufn = Ab + ((r + 1) & 1) * 34 * CHS;
            if (stager) {
                *(bf16x8*)&bufn[slot * CHS + c16 * 16] = ra;
                *(bf16x8*)&bufn[slot * CHS + c16 * 16 + 8] = rb;
            }
            if (r + 2 < nr) load_row(r + 2, ra, rb);
        }
#pragma unroll
        for (int kw = 0; kw < 3; ++kw) {
            const bf16x8 b0 = cb[kw * 2];
            const bf16x8 b1 = cb[kw * 2 + 1];
#pragma unroll
            for (int m = 0; m < 2; ++m) {
                const __hip_bfloat16* ap = buf + (m * 16 + l15 + kw) * CHS + quad * 8;
                const bf16x8 a0 = *(const bf16x8*)(ap);
                const bf16x8 a1 = *(const bf16x8*)(ap + 32);
                acc[m] = __builtin_amdgcn_mfma_f32_16x16x32_bf16(a0, b0, acc[m], 0, 0, 0);
                acc[m] = __builtin_amdgcn_mfma_f32_16x16x32_bf16(a1, b1, acc[m], 0, 0, 0);
            }
        }
#pragma unroll
        for (int q2 = 0; q2 < 6; ++q2) cb[q2] = nb[q2];
        if (r + 2 < nr) loadB(r + 2, nb);
        __syncthreads();
    }

    const int posbase = t * HW_ + h * W_ + w0;

    if constexpr (CONV1) {
        float* ts = smem;                      // [32 pos][68 ch]
        const float bv = bias[n];
#pragma unroll
        for (int m = 0; m < 2; ++m)
#pragma unroll
            for (int r = 0; r < 4; ++r) {
                float v = acc[m][r] + bv;
                v = (v >= 0.f) ? v : 0.01f * v;
                ts[(m * 16 + quad * 4 + r) * 68 + n] = v;
            }
        __syncthreads();
#pragma unroll
        for (int c = 0; c < 2; ++c) {
            const int flat4 = c * 256 + tid;
            const int w = flat4 >> 4, cg = flat4 & 15;
            const float4 v4 = *(const float4*)&ts[w * 68 + cg * 4];
            __hip_bfloat16 hb[4] = {__float2bfloat16(v4.x), __float2bfloat16(v4.y),
                                    __float2bfloat16(v4.z), __float2bfloat16(v4.w)};
            *(uint2*)&out_cl_b16[(posbase + w) * C_ + cg * 4] = *(const uint2*)hb;
        }
    } else {
        if (n < nco) {
            const float bv = bias[n];
#pragma unroll
            for (int m = 0; m < 2; ++m) {
                floatx4 v = acc[m];
                v[0] += bv; v[1] += bv; v[2] += bv; v[3] += bv;
                *(floatx4*)&out_cf[n * THW_ + posbase + m * 16 + quad * 4] = v;
            }
        }
    }
}

// ---------------------------------------------------------------------------
// BARRIER-FREE per-wave MFMA deformable conv (R10 rewrite).
//  Wave tile = 16 positions x 32 couts (m=1, n=2 subtiles of 16).
//  Lane (l15, quad) gathers its OWN position's 4 corners at channels
//  quad*8 / quad*8+32 — exactly the 16x16x32 A-fragment layout — blends in
//  regs, MFMAs directly. NO LDS A-panel, NO __syncthreads, 1-deep gather
//  pipeline with named state only (no dynamically-indexed arrays -> no spill).
//  Block 256 thr = 4 waves: (pos-group 0/1) x (co-half 0/1); grid T*H*2.
//  Gathers duplicated 2x across co-halves (L2-absorbed).
// ---------------------------------------------------------------------------
struct G16 {
    bf16x8 c00a, c00b, c01a, c01b, c10a, c10b, c11a, c11b;
    float w00, w01, w10, w11;
};

__global__ __launch_bounds__(256) void deform_mfma_kernel(
    const __hip_bfloat16* __restrict__ y1b, const float* __restrict__ off,
    const __hip_bfloat16* __restrict__ wds, const float* __restrict__ bd,
    const __hip_bfloat16* __restrict__ xclb, const __hip_bfloat16* __restrict__ wrs,
    const float* __restrict__ br, float* __restrict__ out) {
    const int tid = threadIdx.x;
    const int wv = tid >> 6;
    const int lane = tid & 63;
    const int l15 = lane & 15;
    const int quad = lane >> 4;
    const int wh = blockIdx.x & 1;
    const int h = (blockIdx.x >> 1) & 63;
    const int t = blockIdx.x >> 7;
    const int w0 = wh * 32;
    const int pg = wv >> 1;                  // pos-group: positions w0+pg*16 .. +16
    const int chf = wv & 1;                  // co-half: couts chf*32 .. +32
    const int wpos = w0 + pg * 16 + l15;     // this lane's w position
    const int posbase = t * HW_ + h * W_;
    const int mypos = posbase + wpos;

    floatx4 acc0 = (floatx4){0.f, 0.f, 0.f, 0.f};
    floatx4 acc1 = (floatx4){0.f, 0.f, 0.f, 0.f};

    const int k0 = (t == 0) ? 9 : 0;
    const int k1 = (t == T_ - 1) ? 18 : KTAPS;

    auto load_off = [&](int k, float& dh, float& dw) {
        dh = off[(2 * k) * THW_ + mypos];
        dw = off[(2 * k + 1) * THW_ + mypos];
    };
    auto gather = [&](int k, float dh, float dw, G16& g) {
        const int kt = k / 9, kh = (k / 3) % 3, kw = k % 3;
        const int t_in = t - 1 + kt;                    // in range by k0/k1
        const float hs = (float)(h - 1 + kh) + dh;
        const float wsv = (float)(wpos - 1 + kw) + dw;
        const float h0f = floorf(hs), w0f = floorf(wsv);
        const float fh = hs - h0f, fw = wsv - w0f;
        const int h0i = (int)h0f, w0i = (int)w0f;
        const int h1i = h0i + 1, w1i = w0i + 1;
        const float m_h0 = ((unsigned)h0i < H_) ? 1.f : 0.f;
        const float m_h1 = ((unsigned)h1i < H_) ? 1.f : 0.f;
        const float m_w0 = ((unsigned)w0i < W_) ? 1.f : 0.f;
        const float m_w1 = ((unsigned)w1i < W_) ? 1.f : 0.f;
        g.w00 = (1.f - fh) * (1.f - fw) * m_h0 * m_w0;
        g.w01 = (1.f - fh) * fw * m_h0 * m_w1;
        g.w10 = fh * (1.f - fw) * m_h1 * m_w0;
        g.w11 = fh * fw * m_h1 * m_w1;
        const int h0c = min(max(h0i, 0), H_ - 1);
        const int h1c = min(max(h1i, 0), H_ - 1);
        const int w0c = min(max(w0i, 0), W_ - 1);
        const int w1c = min(max(w1i, 0), W_ - 1);
        const int tb = t_in * HW_;
        const __hip_bfloat16* p00 = y1b + (tb + h0c * W_ + w0c) * C_ + quad * 8;
        const __hip_bfloat16* p01 = y1b + (tb + h0c * W_ + w1c) * C_ + quad * 8;
        const __hip_bfloat16* p10 = y1b + (tb + h1c * W_ + w0c) * C_ + quad * 8;
        const __hip_bfloat16* p11 = y1b + (tb + h1c * W_ + w1c) * C_ + quad * 8;
        g.c00a = *(const bf16x8*)(p00); g.c00b = *(const bf16x8*)(p00 + 32);
        g.c01a = *(const bf16x8*)(p01); g.c01b = *(const bf16x8*)(p01 + 32);
        g.c10a = *(const bf16x8*)(p10); g.c10b = *(const bf16x8*)(p10 + 32);
        g.c11a = *(const bf16x8*)(p11); g.c11b = *(const bf16x8*)(p11 + 32);
    };
    auto blend2 = [&](const G16& g, bf16x8& a0, bf16x8& a1) {
        union U { bf16x8 v; __hip_bfloat16 e[8]; };
        U u00, u01, u10, u11, r;
#pragma unroll
        for (int s = 0; s < 2; ++s) {
            u00.v = s ? g.c00b : g.c00a;
            u01.v = s ? g.c01b : g.c01a;
            u10.v = s ? g.c10b : g.c10a;
            u11.v = s ? g.c11b : g.c11a;
#pragma unroll
            for (int j = 0; j < 8; ++j) {
                float f = g.w00 * __bfloat162float(u00.e[j]) + g.w01 * __bfloat162float(u01.e[j]) +
                          g.w10 * __bfloat162float(u10.e[j]) + g.w11 * __bfloat162float(u11.e[j]);
                r.e[j] = __float2bfloat16(f);
            }
            if (s) a1 = r.v; else a0 = r.v;
        }
    };

    // ---- pipeline: 1-deep gather prefetch, all state named ----
    G16 g;
    float dh, dw;
    load_off(k0, dh, dw);
    gather(k0, dh, dw, g);
    load_off(k0 + 1, dh, dw);                 // k1-k0 >= 9, always valid

    const __hip_bfloat16* wdbase = wds + chf * 2048 + lane * 8;
    for (int k = k0; k < k1; ++k) {
        bf16x8 a0, a1;
        blend2(g, a0, a1);                    // consumes loads issued last iter
        if (k + 1 < k1) {
            gather(k + 1, dh, dw, g);         // reuse slot after blend consumed it
            if (k + 2 < k1) load_off(k + 2, dh, dw);
        }
        const __hip_bfloat16* bp = wdbase + k * 4096;
        const bf16x8 b00 = *(const bf16x8*)(bp);          // n1=0, s=0
        const bf16x8 b01 = *(const bf16x8*)(bp + 512);    // n1=0, s=1
        const bf16x8 b10 = *(const bf16x8*)(bp + 1024);   // n1=1, s=0
        const bf16x8 b11 = *(const bf16x8*)(bp + 1536);   // n1=1, s=1
        acc0 = __builtin_amdgcn_mfma_f32_16x16x32_bf16(a0, b00, acc0, 0, 0, 0);
        acc0 = __builtin_amdgcn_mfma_f32_16x16x32_bf16(a1, b01, acc0, 0, 0, 0);
        acc1 = __builtin_amdgcn_mfma_f32_16x16x32_bf16(a0, b10, acc1, 0, 0, 0);
        acc1 = __builtin_amdgcn_mfma_f32_16x16x32_bf16(a1, b11, acc1, 0, 0, 0);
    }

    // ---- residual 1x1 conv on x: 4 MFMAs (done at end to keep regs short-lived)
    floatx4 r0 = (floatx4){0.f, 0.f, 0.f, 0.f};
    floatx4 r1 = (floatx4){0.f, 0.f, 0.f, 0.f};
    {
        const __hip_bfloat16* ap = xclb + mypos * C_ + quad * 8;
        const bf16x8 ra0 = *(const bf16x8*)(ap);
        const bf16x8 ra1 = *(const bf16x8*)(ap + 32);
        const __hip_bfloat16* rp = wrs + chf * 2048 + lane * 8;
        const bf16x8 rb00 = *(const bf16x8*)(rp);
        const bf16x8 rb01 = *(const bf16x8*)(rp + 512);
        const bf16x8 rb10 = *(const bf16x8*)(rp + 1024);
        const bf16x8 rb11 = *(const bf16x8*)(rp + 1536);
        r0 = __builtin_amdgcn_mfma_f32_16x16x32_bf16(ra0, rb00, r0, 0, 0, 0);
        r0 = __builtin_amdgcn_mfma_f32_16x16x32_bf16(ra1, rb01, r0, 0, 0, 0);
        r1 = __builtin_amdgcn_mfma_f32_16x16x32_bf16(ra0, rb10, r1, 0, 0, 0);
        r1 = __builtin_amdgcn_mfma_f32_16x16x32_bf16(ra1, rb11, r1, 0, 0, 0);
    }

    // ---- epilogue: lrelu(deform + bd) + (residual + br) ----
    // D layout: col(lane&15)=cout-within-16, row(quad*4+reg)=pos-within-16.
    const int n0 = chf * 32 + l15;
    const float bd0 = bd[n0], bd1 = bd[n0 + 16];
    const float br0 = br[n0], br1 = br[n0 + 16];
    const int pbase = posbase + w0 + pg * 16 + quad * 4;
    floatx4 o0, o1;
#pragma unroll
    for (int r = 0; r < 4; ++r) {
        float v0 = acc0[r] + bd0;
        v0 = (v0 >= 0.f) ? v0 : 0.01f * v0;
        o0[r] = v0 + r0[r] + br0;
        float v1 = acc1[r] + bd1;
        v1 = (v1 >= 0.f) ? v1 : 0.01f * v1;
        o1[r] = v1 + r1[r] + br1;
    }
    *(floatx4*)&out[n0 * THW_ + pbase] = o0;
    *(floatx4*)&out[(n0 + 16) * THW_ + pbase] = o1;
}

// ---------------------------------------------------------------------------
extern "C" void kernel_launch(void* const* d_in, const int* in_sizes, int n_in,
                              void* d_out, int out_size, void* d_ws, size_t ws_size,
                              hipStream_t stream) {
    const float* x    = (const float*)d_in[0];
    const float* W1   = (const float*)d_in[1];
    const float* b1   = (const float*)d_in[2];
    const float* Woff = (const float*)d_in[3];
    const float* boff = (const float*)d_in[4];
    const float* Wd   = (const float*)d_in[5];
    const float* bd   = (const float*)d_in[6];
    const float* Wr   = (const float*)d_in[7];
    const float* br   = (const float*)d_in[8];
    float* out = (float*)d_out;

    float* ws = (float*)d_ws;
    float* offcf = ws;                                         // 1,769,472 f
    __hip_bfloat16* xclb  = (__hip_bfloat16*)(ws + 1769472);   // 2,097,152 bf16
    __hip_bfloat16* y1b   = (__hip_bfloat16*)(ws + 2818048);   // 2,097,152 bf16
    __hip_bfloat16* w1s   = (__hip_bfloat16*)(ws + 3866624);   //   110,592 bf16
    __hip_bfloat16* woffs = (__hip_bfloat16*)(ws + 3921920);   //   110,592 bf16
    __hip_bfloat16* wdsb  = (__hip_bfloat16*)(ws + 3977216);   //   110,592 bf16
    __hip_bfloat16* wrsb  = (__hip_bfloat16*)(ws + 4032512);   //     4,096 bf16
    // total ~16.1 MB

    prep_kernel<<<(C_ * KDIM + 255) / 256, 256, 0, stream>>>(
        W1, Woff, Wd, Wr, w1s, woffs, wdsb, wrsb);

    to_cl_kernel<<<THW_ / 64, 256, 0, stream>>>(x, xclb);

    conv_mfma_kernel<true><<<dim3(T_ * H_ * 2), 256, 0, stream>>>(
        xclb, w1s, b1, y1b, nullptr, 64);

    conv_mfma_kernel<false><<<dim3(T_ * H_ * 2), 256, 0, stream>>>(
        y1b, woffs, boff, nullptr, offcf, NOFF);

    deform_mfma_kernel<<<dim3(T_ * H_ * 2), 256, 0, stream>>>(
        y1b, offcf, wdsb, bd, xclb, wrsb, br, out);
}

// Round 11
// 215.318 us; speedup vs baseline: 1.3217x; 1.3217x over previous
//
#include <hip/hip_runtime.h>
#include <hip/hip_bf16.h>

// Problem constants (B=1)
#define T_ 8
#define H_ 64
#define W_ 64
#define C_ 64
#define HW_ (H_ * W_)          // 4096
#define THW_ (T_ * H_ * W_)    // 32768
#define KTAPS 27
#define KDIM (C_ * KTAPS)      // 1728
#define NOFF 54
#define CHS 70                 // padded LDS channel stride (bf16) for deform staging

typedef __bf16 bf16x8 __attribute__((ext_vector_type(8)));
typedef float floatx4 __attribute__((ext_vector_type(4)));

// ---------------------------------------------------------------------------
// prep: swizzle weights into MFMA B-fragment order (wave-uniform + lane*16B).
//  ws[tap*4096 + g16*1024 + s*512 + lane*8 + j]
//    = W[co = g16*16 + (lane&15)][cin = s*32 + (lane>>4)*8 + j][tap]
// ---------------------------------------------------------------------------
__global__ void prep_kernel(const float* __restrict__ w1, const float* __restrict__ woff,
                            const float* __restrict__ wd, const float* __restrict__ wr,
                            __hip_bfloat16* __restrict__ w1s, __hip_bfloat16* __restrict__ woffs,
                            __hip_bfloat16* __restrict__ wds, __hip_bfloat16* __restrict__ wrs) {
    int i = blockIdx.x * 256 + threadIdx.x;
    if (i < C_ * KDIM) {
        int j = i & 7, lane = (i >> 3) & 63, s = (i >> 9) & 1, g16 = (i >> 10) & 3, tap = i >> 12;
        int co = g16 * 16 + (lane & 15);
        int cin = s * 32 + (lane >> 4) * 8 + j;
        int src = (co * C_ + cin) * KTAPS + tap;
        w1s[i] = __float2bfloat16(w1[src]);
        woffs[i] = (co < NOFF) ? __float2bfloat16(woff[src]) : __float2bfloat16(0.f);
        wds[i] = __float2bfloat16(wd[src]);
    }
    if (i < C_ * C_) {
        int j = i & 7, lane = (i >> 3) & 63, s = (i >> 9) & 1, g16 = i >> 10;
        int co = g16 * 16 + (lane & 15);
        int cin = s * 32 + (lane >> 4) * 8 + j;
        wrs[i] = __float2bfloat16(wr[co * C_ + cin]);
    }
}

// ---------------------------------------------------------------------------
// x (64,T,H,W) fp32 cf -> xcl (T,H,W,64) bf16 cl, via LDS 64x64 transpose tile
// ---------------------------------------------------------------------------
__global__ __launch_bounds__(256) void to_cl_kernel(const float* __restrict__ x,
                                                    __hip_bfloat16* __restrict__ xcl) {
    __shared__ float tile[64][65];
    const int pos0 = blockIdx.x * 64;
    const int tid = threadIdx.x;
    for (int i = tid; i < 4096; i += 256) {
        int ch = i >> 6, p = i & 63;
        tile[ch][p] = x[ch * THW_ + pos0 + p];
    }
    __syncthreads();
    for (int i = tid; i < 4096; i += 256) {
        int p = i >> 6, ch = i & 63;
        xcl[(pos0 + p) * C_ + ch] = __float2bfloat16(tile[ch][p]);
    }
}

// ---------------------------------------------------------------------------
// BARRIER-FREE per-wave streaming MFMA 3x3x3 conv (R11 rewrite).
//  Wave tile = 16 pos x 32 couts; block 256 = 4 waves (pg 0/1 x chf 0/1),
//  block covers (t,h,w-half): 32 pos x 64 co. Grid T*H*2 = 1024.
//  Per tap: 2 A-loads direct from channel-last global (per-lane w-edge zero),
//  4 coalesced swizzled B-loads, 4 MFMAs. No LDS in K-loop, no barriers.
//  Conv A-addresses are affine -> loads pipeline freely (unlike deform R10).
// ---------------------------------------------------------------------------
template <bool CONV1>
__global__ __launch_bounds__(256) void conv_stream_kernel(
    const __hip_bfloat16* __restrict__ in_cl,
    const __hip_bfloat16* __restrict__ wTs,   // swizzled (27*4096)
    const float* __restrict__ bias,
    __hip_bfloat16* __restrict__ out_cl_b16,  // CONV1: (T,H,W,64)
    float* __restrict__ out_cf) {             // !CONV1: (54,T,H,W)
    __shared__ __hip_bfloat16 ts[CONV1 ? 32 * 72 : 1];   // 4608B bounce (stride 144B = 16B-mult)

    const int tid = threadIdx.x;
    const int wv = tid >> 6;
    const int lane = tid & 63;
    const int l15 = lane & 15;
    const int quad = lane >> 4;
    const int wh = blockIdx.x & 1;
    const int h = (blockIdx.x >> 1) & 63;
    const int t = blockIdx.x >> 7;
    const int w0 = wh * 32;
    const int pg = wv >> 1;                   // position group (16 pos)
    const int chf = wv & 1;                   // cout half (32 co)
    const int wpos = w0 + pg * 16 + l15;      // this lane's w position (A row)
    const int posbase = t * HW_ + h * W_;

    floatx4 acc0 = (floatx4){0.f, 0.f, 0.f, 0.f};
    floatx4 acc1 = (floatx4){0.f, 0.f, 0.f, 0.f};
    const bf16x8 z = {};
    const __hip_bfloat16* wb = wTs + chf * 2048 + lane * 8;

    const int ktlo = (t == 0) ? 1 : 0;
    const int kthi = (t == T_ - 1) ? 2 : 3;

    for (int kt = ktlo; kt < kthi; ++kt) {
        const int t_in = t - 1 + kt;
#pragma unroll 1
        for (int kh = 0; kh < 3; ++kh) {
            const int h_in = h - 1 + kh;
            if ((unsigned)h_in >= H_) continue;           // block-uniform
            const int rowbase = t_in * HW_ + h_in * W_;
#pragma unroll
            for (int kw = 0; kw < 3; ++kw) {
                const int tap = kt * 9 + kh * 3 + kw;
                const int w_in = wpos - 1 + kw;
                const bool v = (unsigned)w_in < W_;       // per-lane edge
                const int wc = v ? w_in : 0;
                const __hip_bfloat16* ap = in_cl + (rowbase + wc) * C_ + quad * 8;
                bf16x8 a0 = *(const bf16x8*)(ap);
                bf16x8 a1 = *(const bf16x8*)(ap + 32);
                a0 = v ? a0 : z;
                a1 = v ? a1 : z;
                const __hip_bfloat16* bp = wb + tap * 4096;
                const bf16x8 b00 = *(const bf16x8*)(bp);          // n1=0,s=0
                const bf16x8 b01 = *(const bf16x8*)(bp + 512);    // n1=0,s=1
                const bf16x8 b10 = *(const bf16x8*)(bp + 1024);   // n1=1,s=0
                const bf16x8 b11 = *(const bf16x8*)(bp + 1536);   // n1=1,s=1
                acc0 = __builtin_amdgcn_mfma_f32_16x16x32_bf16(a0, b00, acc0, 0, 0, 0);
                acc0 = __builtin_amdgcn_mfma_f32_16x16x32_bf16(a1, b01, acc0, 0, 0, 0);
                acc1 = __builtin_amdgcn_mfma_f32_16x16x32_bf16(a0, b10, acc1, 0, 0, 0);
                acc1 = __builtin_amdgcn_mfma_f32_16x16x32_bf16(a1, b11, acc1, 0, 0, 0);
            }
        }
    }

    // D layout (verified R9/R10): l15 = cout (from B), quad*4+r = position (from A)
    const int n0 = chf * 32 + l15;

    if constexpr (CONV1) {
        const float bv0 = bias[n0], bv1 = bias[n0 + 16];
#pragma unroll
        for (int r = 0; r < 4; ++r) {
            const int p = pg * 16 + quad * 4 + r;
            float v0 = acc0[r] + bv0;
            v0 = (v0 >= 0.f) ? v0 : 0.01f * v0;
            float v1 = acc1[r] + bv1;
            v1 = (v1 >= 0.f) ? v1 : 0.01f * v1;
            ts[p * 72 + n0] = __float2bfloat16(v0);
            ts[p * 72 + n0 + 16] = __float2bfloat16(v1);
        }
        __syncthreads();
        // coalesced channel-last store: 32 pos x 64 ch, 16B per thread
        {
            const int p = tid >> 3, ck = tid & 7;
            const uint4 v4 = *(const uint4*)&ts[p * 72 + ck * 8];
            *(uint4*)&out_cl_b16[(posbase + w0 + p) * C_ + ck * 8] = v4;
        }
    } else {
        const int pb = posbase + w0 + pg * 16 + quad * 4;
        {
            const float bv = bias[n0];                    // n0 <= 47 < 54 always
            floatx4 o;
#pragma unroll
            for (int r = 0; r < 4; ++r) o[r] = acc0[r] + bv;
            *(floatx4*)&out_cf[n0 * THW_ + pb] = o;
        }
        if (n0 + 16 < NOFF) {
            const float bv = bias[n0 + 16];
            floatx4 o;
#pragma unroll
            for (int r = 0; r < 4; ++r) o[r] = acc1[r] + bv;
            *(floatx4*)&out_cf[(n0 + 16) * THW_ + pb] = o;
        }
    }
}

// ---------------------------------------------------------------------------
// MFMA deformable conv — EXACT revert to passing R9 (66.8 µs): cooperative
// LDS-staged A, 2-deep gather pipeline with NAMED slots (gA/gB, 2x-unrolled
// tap loop), swizzled coalesced B, fused 1x1 MFMA residual.
// ---------------------------------------------------------------------------
struct Gath {
    bf16x8 c00, c01, c10, c11;
    float w00, w01, w10, w11;
};

__global__ __launch_bounds__(256) void deform_mfma_kernel(
    const __hip_bfloat16* __restrict__ y1b, const float* __restrict__ off,
    const __hip_bfloat16* __restrict__ wds, const float* __restrict__ bd,
    const __hip_bfloat16* __restrict__ xclb, const __hip_bfloat16* __restrict__ wrs,
    const float* __restrict__ br, float* __restrict__ out) {
    __shared__ __hip_bfloat16 Abuf[2][32 * CHS];     // 8960 B

    const int tid = threadIdx.x;
    const int wv = tid >> 6;
    const int lane = tid & 63;
    const int l15 = lane & 15;
    const int quad = lane >> 4;
    const int wh = blockIdx.x & 1;
    const int h = (blockIdx.x >> 1) & 63;
    const int t = blockIdx.x >> 7;
    const int w0 = wh * 32;
    const int n = wv * 16 + l15;
    const int posbase = t * HW_ + h * W_ + w0;
    const int cpos = tid >> 3;               // position 0..31
    const int c8 = tid & 7;                  // 8-ch chunk

    floatx4 acc[2], racc[2];
#pragma unroll
    for (int m = 0; m < 2; ++m) {
        acc[m] = (floatx4){0.f, 0.f, 0.f, 0.f};
        racc[m] = (floatx4){0.f, 0.f, 0.f, 0.f};
    }

    // ---- residual 1x1 conv on x (swizzled B, coalesced) ----
    {
        const bf16x8 rb0 = *(const bf16x8*)(wrs + wv * 1024 + lane * 8);
        const bf16x8 rb1 = *(const bf16x8*)(wrs + wv * 1024 + lane * 8 + 512);
#pragma unroll
        for (int m = 0; m < 2; ++m) {
            const __hip_bfloat16* ap = xclb + (posbase + m * 16 + l15) * C_ + quad * 8;
            const bf16x8 a0 = *(const bf16x8*)(ap);
            const bf16x8 a1 = *(const bf16x8*)(ap + 32);
            racc[m] = __builtin_amdgcn_mfma_f32_16x16x32_bf16(a0, rb0, racc[m], 0, 0, 0);
            racc[m] = __builtin_amdgcn_mfma_f32_16x16x32_bf16(a1, rb1, racc[m], 0, 0, 0);
        }
    }

    const int k0 = (t == 0) ? 9 : 0;
    const int k1 = (t == T_ - 1) ? 18 : KTAPS;

    auto load_off = [&](int k, float& dh, float& dw) {
        dh = off[(2 * k) * THW_ + posbase + cpos];
        dw = off[(2 * k + 1) * THW_ + posbase + cpos];
    };
    auto gather = [&](int k, float dh, float dw, Gath& g) {
        const int kt = k / 9, kh = (k / 3) % 3, kw = k % 3;
        const int t_in = t - 1 + kt;
        const float hs = (float)(h - 1 + kh) + dh;
        const float wsv = (float)(w0 + cpos - 1 + kw) + dw;
        const float h0f = floorf(hs), w0f = floorf(wsv);
        const float fh = hs - h0f, fw = wsv - w0f;
        const int h0i = (int)h0f, w0i = (int)w0f;
        const int h1i = h0i + 1, w1i = w0i + 1;
        const float m_h0 = ((unsigned)h0i < H_) ? 1.f : 0.f;
        const float m_h1 = ((unsigned)h1i < H_) ? 1.f : 0.f;
        const float m_w0 = ((unsigned)w0i < W_) ? 1.f : 0.f;
        const float m_w1 = ((unsigned)w1i < W_) ? 1.f : 0.f;
        g.w00 = (1.f - fh) * (1.f - fw) * m_h0 * m_w0;
        g.w01 = (1.f - fh) * fw * m_h0 * m_w1;
        g.w10 = fh * (1.f - fw) * m_h1 * m_w0;
        g.w11 = fh * fw * m_h1 * m_w1;
        const int h0c = min(max(h0i, 0), H_ - 1);
        const int h1c = min(max(h1i, 0), H_ - 1);
        const int w0c = min(max(w0i, 0), W_ - 1);
        const int w1c = min(max(w1i, 0), W_ - 1);
        const int tb = t_in * HW_;
        g.c00 = *(const bf16x8*)(y1b + (tb + h0c * W_ + w0c) * C_ + c8 * 8);
        g.c01 = *(const bf16x8*)(y1b + (tb + h0c * W_ + w1c) * C_ + c8 * 8);
        g.c10 = *(const bf16x8*)(y1b + (tb + h1c * W_ + w0c) * C_ + c8 * 8);
        g.c11 = *(const bf16x8*)(y1b + (tb + h1c * W_ + w1c) * C_ + c8 * 8);
    };
    auto blend = [&](const Gath& g, bf16x8& o) {
        union U { bf16x8 v; __hip_bfloat16 e[8]; };
        U a00, a01, a10, a11, r;
        a00.v = g.c00; a01.v = g.c01; a10.v = g.c10; a11.v = g.c11;
#pragma unroll
        for (int j = 0; j < 8; ++j) {
            float f = g.w00 * __bfloat162float(a00.e[j]) + g.w01 * __bfloat162float(a01.e[j]) +
                      g.w10 * __bfloat162float(a10.e[j]) + g.w11 * __bfloat162float(a11.e[j]);
            r.e[j] = __float2bfloat16(f);
        }
        o = r.v;
    };
    auto loadBd = [&](int k, bf16x8& B0, bf16x8& B1) {
        const __hip_bfloat16* p = wds + k * 4096 + wv * 1024 + lane * 8;
        B0 = *(const bf16x8*)(p);
        B1 = *(const bf16x8*)(p + 512);
    };

    // ---- named pipeline state (NO dynamically-indexed arrays) ----
    Gath gA, gB;
    bf16x8 bl;
    bf16x8 cb0, cb1, nb0, nb1;
    float oh2, ow2;

    auto step = [&](int k, __hip_bfloat16* buf, Gath& gSelf, Gath& gOther) {
        *(bf16x8*)&buf[cpos * CHS + c8 * 8] = bl;
        if (k + 2 < k1) {
            gather(k + 2, oh2, ow2, gSelf);           // tap k's slot: already consumed
            if (k + 3 < k1) load_off(k + 3, oh2, ow2);
        }
        __syncthreads();

        const bf16x8 b0 = cb0;
        const bf16x8 b1 = cb1;
#pragma unroll
        for (int m = 0; m < 2; ++m) {
            const __hip_bfloat16* ap = buf + (m * 16 + l15) * CHS + quad * 8;
            const bf16x8 a0 = *(const bf16x8*)(ap);
            const bf16x8 a1 = *(const bf16x8*)(ap + 32);
            acc[m] = __builtin_amdgcn_mfma_f32_16x16x32_bf16(a0, b0, acc[m], 0, 0, 0);
            acc[m] = __builtin_amdgcn_mfma_f32_16x16x32_bf16(a1, b1, acc[m], 0, 0, 0);
        }
        if (k + 1 < k1) {
            blend(gOther, bl);                        // tap k+1
            cb0 = nb0; cb1 = nb1;
            if (k + 2 < k1) loadBd(k + 2, nb0, nb1);
        }
    };

    // ---- prologue: gathers 2 taps deep, B 1 tap deep ----
    {
        float dh0, dw0, dh1, dw1;
        load_off(k0, dh0, dw0);
        load_off(k0 + 1, dh1, dw1);
        load_off(k0 + 2, oh2, ow2);
        gather(k0, dh0, dw0, gA);
        gather(k0 + 1, dh1, dw1, gB);
        loadBd(k0, cb0, cb1);
        loadBd(k0 + 1, nb0, nb1);
        blend(gA, bl);
    }

    // ---- main loop, 2x unrolled: even kr -> (buf0, gA), odd kr -> (buf1, gB)
    int k = k0;
    for (; k + 1 < k1; k += 2) {
        step(k, Abuf[0], gA, gB);
        step(k + 1, Abuf[1], gB, gA);
    }
    if (k < k1) step(k, Abuf[0], gA, gB);             // tail (nk odd: kr even -> gA/buf0)

    // ---- epilogue: lrelu(deform + bd) + (residual + br) ----
    const float bdv = bd[n];
    const float brv = br[n];
#pragma unroll
    for (int m = 0; m < 2; ++m) {
        floatx4 o;
#pragma unroll
        for (int r = 0; r < 4; ++r) {
            float v = acc[m][r] + bdv;
            v = (v >= 0.f) ? v : 0.01f * v;
            o[r] = v + racc[m][r] + brv;
        }
        *(floatx4*)&out[n * THW_ + posbase + m * 16 + quad * 4] = o;
    }
}

// ---------------------------------------------------------------------------
extern "C" void kernel_launch(void* const* d_in, const int* in_sizes, int n_in,
                              void* d_out, int out_size, void* d_ws, size_t ws_size,
                              hipStream_t stream) {
    const float* x    = (const float*)d_in[0];
    const float* W1   = (const float*)d_in[1];
    const float* b1   = (const float*)d_in[2];
    const float* Woff = (const float*)d_in[3];
    const float* boff = (const float*)d_in[4];
    const float* Wd   = (const float*)d_in[5];
    const float* bd   = (const float*)d_in[6];
    const float* Wr   = (const float*)d_in[7];
    const float* br   = (const float*)d_in[8];
    float* out = (float*)d_out;

    float* ws = (float*)d_ws;
    float* offcf = ws;                                         // 1,769,472 f
    __hip_bfloat16* xclb  = (__hip_bfloat16*)(ws + 1769472);   // 2,097,152 bf16
    __hip_bfloat16* y1b   = (__hip_bfloat16*)(ws + 2818048);   // 2,097,152 bf16
    __hip_bfloat16* w1s   = (__hip_bfloat16*)(ws + 3866624);   //   110,592 bf16
    __hip_bfloat16* woffs = (__hip_bfloat16*)(ws + 3921920);   //   110,592 bf16
    __hip_bfloat16* wdsb  = (__hip_bfloat16*)(ws + 3977216);   //   110,592 bf16
    __hip_bfloat16* wrsb  = (__hip_bfloat16*)(ws + 4032512);   //     4,096 bf16
    // total ~16.1 MB

    prep_kernel<<<(C_ * KDIM + 255) / 256, 256, 0, stream>>>(
        W1, Woff, Wd, Wr, w1s, woffs, wdsb, wrsb);

    to_cl_kernel<<<THW_ / 64, 256, 0, stream>>>(x, xclb);

    conv_stream_kernel<true><<<dim3(T_ * H_ * 2), 256, 0, stream>>>(
        xclb, w1s, b1, y1b, nullptr);

    conv_stream_kernel<false><<<dim3(T_ * H_ * 2), 256, 0, stream>>>(
        y1b, woffs, boff, nullptr, offcf);

    deform_mfma_kernel<<<dim3(T_ * H_ * 2), 256, 0, stream>>>(
        y1b, offcf, wdsb, bd, xclb, wrsb, br, out);
}

// Round 12
// 202.004 us; speedup vs baseline: 1.4088x; 1.0659x over previous
//
#include <hip/hip_runtime.h>
#include <hip/hip_bf16.h>

// Problem constants (B=1)
#define T_ 8
#define H_ 64
#define W_ 64
#define C_ 64
#define HW_ (H_ * W_)          // 4096
#define THW_ (T_ * H_ * W_)    // 32768
#define KTAPS 27
#define KDIM (C_ * KTAPS)      // 1728
#define NOFF 54
#define CHS 70                 // padded LDS channel stride (bf16) for deform staging
#define OSTR 56                // LDS offsets panel stride (floats)

typedef __bf16 bf16x8 __attribute__((ext_vector_type(8)));
typedef float floatx4 __attribute__((ext_vector_type(4)));

// ---------------------------------------------------------------------------
// prep: swizzle weights into MFMA B-fragment order (wave-uniform + lane*16B).
//  ws[tap*4096 + g16*1024 + s*512 + lane*8 + j]
//    = W[co = g16*16 + (lane&15)][cin = s*32 + (lane>>4)*8 + j][tap]
// ---------------------------------------------------------------------------
__global__ void prep_kernel(const float* __restrict__ w1, const float* __restrict__ woff,
                            const float* __restrict__ wd, const float* __restrict__ wr,
                            __hip_bfloat16* __restrict__ w1s, __hip_bfloat16* __restrict__ woffs,
                            __hip_bfloat16* __restrict__ wds, __hip_bfloat16* __restrict__ wrs) {
    int i = blockIdx.x * 256 + threadIdx.x;
    if (i < C_ * KDIM) {
        int j = i & 7, lane = (i >> 3) & 63, s = (i >> 9) & 1, g16 = (i >> 10) & 3, tap = i >> 12;
        int co = g16 * 16 + (lane & 15);
        int cin = s * 32 + (lane >> 4) * 8 + j;
        int src = (co * C_ + cin) * KTAPS + tap;
        w1s[i] = __float2bfloat16(w1[src]);
        woffs[i] = (co < NOFF) ? __float2bfloat16(woff[src]) : __float2bfloat16(0.f);
        wds[i] = __float2bfloat16(wd[src]);
    }
    if (i < C_ * C_) {
        int j = i & 7, lane = (i >> 3) & 63, s = (i >> 9) & 1, g16 = i >> 10;
        int co = g16 * 16 + (lane & 15);
        int cin = s * 32 + (lane >> 4) * 8 + j;
        wrs[i] = __float2bfloat16(wr[co * C_ + cin]);
    }
}

// ---------------------------------------------------------------------------
// x (64,T,H,W) fp32 cf -> xcl (T,H,W,64) bf16 cl, via LDS 64x64 transpose tile
// ---------------------------------------------------------------------------
__global__ __launch_bounds__(256) void to_cl_kernel(const float* __restrict__ x,
                                                    __hip_bfloat16* __restrict__ xcl) {
    __shared__ float tile[64][65];
    const int pos0 = blockIdx.x * 64;
    const int tid = threadIdx.x;
    for (int i = tid; i < 4096; i += 256) {
        int ch = i >> 6, p = i & 63;
        tile[ch][p] = x[ch * THW_ + pos0 + p];
    }
    __syncthreads();
    for (int i = tid; i < 4096; i += 256) {
        int p = i >> 6, ch = i & 63;
        xcl[(pos0 + p) * C_ + ch] = __float2bfloat16(tile[ch][p]);
    }
}

// ---------------------------------------------------------------------------
// BARRIER-FREE per-wave streaming MFMA 3x3x3 conv (unchanged from R11, used
// for conv1 only now). Wave tile = 16 pos x 32 couts; block = 32 pos x 64 co.
// ---------------------------------------------------------------------------
__global__ __launch_bounds__(256) void conv_stream_kernel(
    const __hip_bfloat16* __restrict__ in_cl,
    const __hip_bfloat16* __restrict__ wTs,   // swizzled (27*4096)
    const float* __restrict__ bias,
    __hip_bfloat16* __restrict__ out_cl_b16) {
    __shared__ __hip_bfloat16 ts[32 * 72];    // 4608B bounce

    const int tid = threadIdx.x;
    const int wv = tid >> 6;
    const int lane = tid & 63;
    const int l15 = lane & 15;
    const int quad = lane >> 4;
    const int wh = blockIdx.x & 1;
    const int h = (blockIdx.x >> 1) & 63;
    const int t = blockIdx.x >> 7;
    const int w0 = wh * 32;
    const int pg = wv >> 1;
    const int chf = wv & 1;
    const int wpos = w0 + pg * 16 + l15;
    const int posbase = t * HW_ + h * W_;

    floatx4 acc0 = (floatx4){0.f, 0.f, 0.f, 0.f};
    floatx4 acc1 = (floatx4){0.f, 0.f, 0.f, 0.f};
    const bf16x8 z = {};
    const __hip_bfloat16* wb = wTs + chf * 2048 + lane * 8;

    const int ktlo = (t == 0) ? 1 : 0;
    const int kthi = (t == T_ - 1) ? 2 : 3;

    for (int kt = ktlo; kt < kthi; ++kt) {
        const int t_in = t - 1 + kt;
#pragma unroll 1
        for (int kh = 0; kh < 3; ++kh) {
            const int h_in = h - 1 + kh;
            if ((unsigned)h_in >= H_) continue;
            const int rowbase = t_in * HW_ + h_in * W_;
#pragma unroll
            for (int kw = 0; kw < 3; ++kw) {
                const int tap = kt * 9 + kh * 3 + kw;
                const int w_in = wpos - 1 + kw;
                const bool v = (unsigned)w_in < W_;
                const int wc = v ? w_in : 0;
                const __hip_bfloat16* ap = in_cl + (rowbase + wc) * C_ + quad * 8;
                bf16x8 a0 = *(const bf16x8*)(ap);
                bf16x8 a1 = *(const bf16x8*)(ap + 32);
                a0 = v ? a0 : z;
                a1 = v ? a1 : z;
                const __hip_bfloat16* bp = wb + tap * 4096;
                const bf16x8 b00 = *(const bf16x8*)(bp);
                const bf16x8 b01 = *(const bf16x8*)(bp + 512);
                const bf16x8 b10 = *(const bf16x8*)(bp + 1024);
                const bf16x8 b11 = *(const bf16x8*)(bp + 1536);
                acc0 = __builtin_amdgcn_mfma_f32_16x16x32_bf16(a0, b00, acc0, 0, 0, 0);
                acc0 = __builtin_amdgcn_mfma_f32_16x16x32_bf16(a1, b01, acc0, 0, 0, 0);
                acc1 = __builtin_amdgcn_mfma_f32_16x16x32_bf16(a0, b10, acc1, 0, 0, 0);
                acc1 = __builtin_amdgcn_mfma_f32_16x16x32_bf16(a1, b11, acc1, 0, 0, 0);
            }
        }
    }

    const int n0 = chf * 32 + l15;
    const float bv0 = bias[n0], bv1 = bias[n0 + 16];
#pragma unroll
    for (int r = 0; r < 4; ++r) {
        const int p = pg * 16 + quad * 4 + r;
        float v0 = acc0[r] + bv0;
        v0 = (v0 >= 0.f) ? v0 : 0.01f * v0;
        float v1 = acc1[r] + bv1;
        v1 = (v1 >= 0.f) ? v1 : 0.01f * v1;
        ts[p * 72 + n0] = __float2bfloat16(v0);
        ts[p * 72 + n0 + 16] = __float2bfloat16(v1);
    }
    __syncthreads();
    {
        const int p = tid >> 3, ck = tid & 7;
        const uint4 v4 = *(const uint4*)&ts[p * 72 + ck * 8];
        *(uint4*)&out_cl_b16[(posbase + w0 + p) * C_ + ck * 8] = v4;
    }
}

// ---------------------------------------------------------------------------
// FUSED offsets-conv + deformable conv + 1x1 residual (R12).
//  Phase 1: per-wave streaming MFMA offsets conv (R11 conv structure) for the
//   block's 32 positions -> LDS offs[32][56] (fp32). One barrier.
//   (Offsets at position p are consumed ONLY by the block owning p.)
//  Phase 2: R9 deform — cooperative LDS-staged A, named 2-deep gather
//   pipeline, swizzled B — with load_off reading LDS instead of global.
// ---------------------------------------------------------------------------
struct Gath {
    bf16x8 c00, c01, c10, c11;
    float w00, w01, w10, w11;
};

__global__ __launch_bounds__(256) void deform_fused_kernel(
    const __hip_bfloat16* __restrict__ y1b,
    const __hip_bfloat16* __restrict__ woffs, const float* __restrict__ boff,
    const __hip_bfloat16* __restrict__ wds, const float* __restrict__ bd,
    const __hip_bfloat16* __restrict__ xclb, const __hip_bfloat16* __restrict__ wrs,
    const float* __restrict__ br, float* __restrict__ out) {
    __shared__ __hip_bfloat16 Abuf[2][32 * CHS];     // 8960 B
    __shared__ float offs[32 * OSTR];                // 7168 B

    const int tid = threadIdx.x;
    const int wv = tid >> 6;
    const int lane = tid & 63;
    const int l15 = lane & 15;
    const int quad = lane >> 4;
    const int wh = blockIdx.x & 1;
    const int h = (blockIdx.x >> 1) & 63;
    const int t = blockIdx.x >> 7;
    const int w0 = wh * 32;
    const int n = wv * 16 + l15;
    const int posbase = t * HW_ + h * W_ + w0;
    const int cpos = tid >> 3;               // position 0..31
    const int c8 = tid & 7;                  // 8-ch chunk

    // ================= Phase 1: offsets conv -> LDS =================
    {
        const int pg = wv >> 1;              // pos group
        const int chf = wv & 1;              // co half
        const int wpos = w0 + pg * 16 + l15;
        floatx4 oa0 = (floatx4){0.f, 0.f, 0.f, 0.f};
        floatx4 oa1 = (floatx4){0.f, 0.f, 0.f, 0.f};
        const bf16x8 z = {};
        const __hip_bfloat16* wb = woffs + chf * 2048 + lane * 8;
        const int ktlo = (t == 0) ? 1 : 0;
        const int kthi = (t == T_ - 1) ? 2 : 3;

        for (int kt = ktlo; kt < kthi; ++kt) {
            const int t_in = t - 1 + kt;
#pragma unroll 1
            for (int kh = 0; kh < 3; ++kh) {
                const int h_in = h - 1 + kh;
                if ((unsigned)h_in >= H_) continue;
                const int rowbase = t_in * HW_ + h_in * W_;
#pragma unroll
                for (int kw = 0; kw < 3; ++kw) {
                    const int tap = kt * 9 + kh * 3 + kw;
                    const int w_in = wpos - 1 + kw;
                    const bool v = (unsigned)w_in < W_;
                    const int wc = v ? w_in : 0;
                    const __hip_bfloat16* ap = y1b + (rowbase + wc) * C_ + quad * 8;
                    bf16x8 a0 = *(const bf16x8*)(ap);
                    bf16x8 a1 = *(const bf16x8*)(ap + 32);
                    a0 = v ? a0 : z;
                    a1 = v ? a1 : z;
                    const __hip_bfloat16* bp = wb + tap * 4096;
                    const bf16x8 b00 = *(const bf16x8*)(bp);
                    const bf16x8 b01 = *(const bf16x8*)(bp + 512);
                    const bf16x8 b10 = *(const bf16x8*)(bp + 1024);
                    const bf16x8 b11 = *(const bf16x8*)(bp + 1536);
                    oa0 = __builtin_amdgcn_mfma_f32_16x16x32_bf16(a0, b00, oa0, 0, 0, 0);
                    oa0 = __builtin_amdgcn_mfma_f32_16x16x32_bf16(a1, b01, oa0, 0, 0, 0);
                    oa1 = __builtin_amdgcn_mfma_f32_16x16x32_bf16(a0, b10, oa1, 0, 0, 0);
                    oa1 = __builtin_amdgcn_mfma_f32_16x16x32_bf16(a1, b11, oa1, 0, 0, 0);
                }
            }
        }
        // D layout: l15 = cout, quad*4+r = pos-within-16 (verified R9/R10/R11)
        const int n0 = chf * 32 + l15;                // 0..15 or 32..47 (<54)
        const float bv0 = boff[n0];
        const float bv1 = (n0 + 16 < NOFF) ? boff[n0 + 16] : 0.f;
#pragma unroll
        for (int r = 0; r < 4; ++r) {
            const int p = pg * 16 + quad * 4 + r;
            offs[p * OSTR + n0] = oa0[r] + bv0;
            if (n0 + 16 < NOFF) offs[p * OSTR + n0 + 16] = oa1[r] + bv1;
        }
    }
    __syncthreads();

    // ================= Phase 2: deform (R9 structure) =================
    floatx4 acc[2], racc[2];
#pragma unroll
    for (int m = 0; m < 2; ++m) {
        acc[m] = (floatx4){0.f, 0.f, 0.f, 0.f};
        racc[m] = (floatx4){0.f, 0.f, 0.f, 0.f};
    }

    // residual 1x1 conv on x (swizzled B, coalesced)
    {
        const bf16x8 rb0 = *(const bf16x8*)(wrs + wv * 1024 + lane * 8);
        const bf16x8 rb1 = *(const bf16x8*)(wrs + wv * 1024 + lane * 8 + 512);
#pragma unroll
        for (int m = 0; m < 2; ++m) {
            const __hip_bfloat16* ap = xclb + (posbase + m * 16 + l15) * C_ + quad * 8;
            const bf16x8 a0 = *(const bf16x8*)(ap);
            const bf16x8 a1 = *(const bf16x8*)(ap + 32);
            racc[m] = __builtin_amdgcn_mfma_f32_16x16x32_bf16(a0, rb0, racc[m], 0, 0, 0);
            racc[m] = __builtin_amdgcn_mfma_f32_16x16x32_bf16(a1, rb1, racc[m], 0, 0, 0);
        }
    }

    const int k0 = (t == 0) ? 9 : 0;
    const int k1 = (t == T_ - 1) ? 18 : KTAPS;

    auto load_off = [&](int k, float& dh, float& dw) {
        dh = offs[cpos * OSTR + 2 * k];
        dw = offs[cpos * OSTR + 2 * k + 1];
    };
    auto gather = [&](int k, float dh, float dw, Gath& g) {
        const int kt = k / 9, kh = (k / 3) % 3, kw = k % 3;
        const int t_in = t - 1 + kt;
        const float hs = (float)(h - 1 + kh) + dh;
        const float wsv = (float)(w0 + cpos - 1 + kw) + dw;
        const float h0f = floorf(hs), w0f = floorf(wsv);
        const float fh = hs - h0f, fw = wsv - w0f;
        const int h0i = (int)h0f, w0i = (int)w0f;
        const int h1i = h0i + 1, w1i = w0i + 1;
        const float m_h0 = ((unsigned)h0i < H_) ? 1.f : 0.f;
        const float m_h1 = ((unsigned)h1i < H_) ? 1.f : 0.f;
        const float m_w0 = ((unsigned)w0i < W_) ? 1.f : 0.f;
        const float m_w1 = ((unsigned)w1i < W_) ? 1.f : 0.f;
        g.w00 = (1.f - fh) * (1.f - fw) * m_h0 * m_w0;
        g.w01 = (1.f - fh) * fw * m_h0 * m_w1;
        g.w10 = fh * (1.f - fw) * m_h1 * m_w0;
        g.w11 = fh * fw * m_h1 * m_w1;
        const int h0c = min(max(h0i, 0), H_ - 1);
        const int h1c = min(max(h1i, 0), H_ - 1);
        const int w0c = min(max(w0i, 0), W_ - 1);
        const int w1c = min(max(w1i, 0), W_ - 1);
        const int tb = t_in * HW_;
        g.c00 = *(const bf16x8*)(y1b + (tb + h0c * W_ + w0c) * C_ + c8 * 8);
        g.c01 = *(const bf16x8*)(y1b + (tb + h0c * W_ + w1c) * C_ + c8 * 8);
        g.c10 = *(const bf16x8*)(y1b + (tb + h1c * W_ + w0c) * C_ + c8 * 8);
        g.c11 = *(const bf16x8*)(y1b + (tb + h1c * W_ + w1c) * C_ + c8 * 8);
    };
    auto blend = [&](const Gath& g, bf16x8& o) {
        union U { bf16x8 v; __hip_bfloat16 e[8]; };
        U a00, a01, a10, a11, r;
        a00.v = g.c00; a01.v = g.c01; a10.v = g.c10; a11.v = g.c11;
#pragma unroll
        for (int j = 0; j < 8; ++j) {
            float f = g.w00 * __bfloat162float(a00.e[j]) + g.w01 * __bfloat162float(a01.e[j]) +
                      g.w10 * __bfloat162float(a10.e[j]) + g.w11 * __bfloat162float(a11.e[j]);
            r.e[j] = __float2bfloat16(f);
        }
        o = r.v;
    };
    auto loadBd = [&](int k, bf16x8& B0, bf16x8& B1) {
        const __hip_bfloat16* p = wds + k * 4096 + wv * 1024 + lane * 8;
        B0 = *(const bf16x8*)(p);
        B1 = *(const bf16x8*)(p + 512);
    };

    // named pipeline state (no dynamically-indexed arrays -> no spill)
    Gath gA, gB;
    bf16x8 bl;
    bf16x8 cb0, cb1, nb0, nb1;
    float oh2, ow2;

    auto step = [&](int k, __hip_bfloat16* buf, Gath& gSelf, Gath& gOther) {
        *(bf16x8*)&buf[cpos * CHS + c8 * 8] = bl;
        if (k + 2 < k1) {
            gather(k + 2, oh2, ow2, gSelf);
            if (k + 3 < k1) load_off(k + 3, oh2, ow2);
        }
        __syncthreads();

        const bf16x8 b0 = cb0;
        const bf16x8 b1 = cb1;
#pragma unroll
        for (int m = 0; m < 2; ++m) {
            const __hip_bfloat16* ap = buf + (m * 16 + l15) * CHS + quad * 8;
            const bf16x8 a0 = *(const bf16x8*)(ap);
            const bf16x8 a1 = *(const bf16x8*)(ap + 32);
            acc[m] = __builtin_amdgcn_mfma_f32_16x16x32_bf16(a0, b0, acc[m], 0, 0, 0);
            acc[m] = __builtin_amdgcn_mfma_f32_16x16x32_bf16(a1, b1, acc[m], 0, 0, 0);
        }
        if (k + 1 < k1) {
            blend(gOther, bl);
            cb0 = nb0; cb1 = nb1;
            if (k + 2 < k1) loadBd(k + 2, nb0, nb1);
        }
    };

    // prologue: gathers 2 taps deep, B 1 tap deep
    {
        float dh0, dw0, dh1, dw1;
        load_off(k0, dh0, dw0);
        load_off(k0 + 1, dh1, dw1);
        load_off(k0 + 2, oh2, ow2);
        gather(k0, dh0, dw0, gA);
        gather(k0 + 1, dh1, dw1, gB);
        loadBd(k0, cb0, cb1);
        loadBd(k0 + 1, nb0, nb1);
        blend(gA, bl);
    }

    // main loop, 2x unrolled: even kr -> (buf0, gA), odd kr -> (buf1, gB)
    int k = k0;
    for (; k + 1 < k1; k += 2) {
        step(k, Abuf[0], gA, gB);
        step(k + 1, Abuf[1], gB, gA);
    }
    if (k < k1) step(k, Abuf[0], gA, gB);

    // epilogue: lrelu(deform + bd) + (residual + br)
    const float bdv = bd[n];
    const float brv = br[n];
#pragma unroll
    for (int m = 0; m < 2; ++m) {
        floatx4 o;
#pragma unroll
        for (int r = 0; r < 4; ++r) {
            float v = acc[m][r] + bdv;
            v = (v >= 0.f) ? v : 0.01f * v;
            o[r] = v + racc[m][r] + brv;
        }
        *(floatx4*)&out[n * THW_ + posbase + m * 16 + quad * 4] = o;
    }
}

// ---------------------------------------------------------------------------
extern "C" void kernel_launch(void* const* d_in, const int* in_sizes, int n_in,
                              void* d_out, int out_size, void* d_ws, size_t ws_size,
                              hipStream_t stream) {
    const float* x    = (const float*)d_in[0];
    const float* W1   = (const float*)d_in[1];
    const float* b1   = (const float*)d_in[2];
    const float* Woff = (const float*)d_in[3];
    const float* boff = (const float*)d_in[4];
    const float* Wd   = (const float*)d_in[5];
    const float* bd   = (const float*)d_in[6];
    const float* Wr   = (const float*)d_in[7];
    const float* br   = (const float*)d_in[8];
    float* out = (float*)d_out;

    float* ws = (float*)d_ws;
    __hip_bfloat16* xclb  = (__hip_bfloat16*)(ws);             // 2,097,152 bf16
    __hip_bfloat16* y1b   = (__hip_bfloat16*)(ws + 1048576);   // 2,097,152 bf16
    __hip_bfloat16* w1s   = (__hip_bfloat16*)(ws + 2097152);   //   110,592 bf16
    __hip_bfloat16* woffs = (__hip_bfloat16*)(ws + 2152448);   //   110,592 bf16
    __hip_bfloat16* wdsb  = (__hip_bfloat16*)(ws + 2207744);   //   110,592 bf16
    __hip_bfloat16* wrsb  = (__hip_bfloat16*)(ws + 2263040);   //     4,096 bf16
    // total ~9.1 MB (offcf eliminated)

    prep_kernel<<<(C_ * KDIM + 255) / 256, 256, 0, stream>>>(
        W1, Woff, Wd, Wr, w1s, woffs, wdsb, wrsb);

    to_cl_kernel<<<THW_ / 64, 256, 0, stream>>>(x, xclb);

    conv_stream_kernel<<<dim3(T_ * H_ * 2), 256, 0, stream>>>(
        xclb, w1s, b1, y1b);

    deform_fused_kernel<<<dim3(T_ * H_ * 2), 256, 0, stream>>>(
        y1b, woffs, boff, wdsb, bd, xclb, wrsb, br, out);
}